// Round 1
// baseline (359.893 us; speedup 1.0000x reference)
//
#include <hip/hip_runtime.h>
#include <stdint.h>

#define B_ 4
#define D_ 256
#define N_ 4096
#define K_ 8192
#define Q_ (B_*N_)   // 16384 queries

typedef __attribute__((ext_vector_type(8))) short bf16x8;
typedef __attribute__((ext_vector_type(4))) float f32x4;

__device__ __forceinline__ unsigned short f32_to_bf16(float f) {
  unsigned u = __float_as_uint(f);
  unsigned r = 0x7FFFu + ((u >> 16) & 1u);
  return (unsigned short)((u + r) >> 16);
}
__device__ __forceinline__ float bf16_to_f32(unsigned short h) {
  return __uint_as_float(((unsigned)h) << 16);
}

// Transpose x [B, D, N] -> xh/xl [Q=B*N, D] bf16 hi/lo split.
__global__ void prep_x_kernel(const float* __restrict__ x,
                              unsigned short* __restrict__ xh,
                              unsigned short* __restrict__ xl) {
  __shared__ float tile[32][33];
  int b = blockIdx.z;
  int d0 = blockIdx.y * 32;
  int n0 = blockIdx.x * 32;
  int tx = threadIdx.x, ty = threadIdx.y;
  const float* xp = x + ((size_t)b * D_ + d0) * N_ + n0;
#pragma unroll
  for (int i = 0; i < 4; ++i)
    tile[ty + 8 * i][tx] = xp[(size_t)(ty + 8 * i) * N_ + tx];
  __syncthreads();
#pragma unroll
  for (int i = 0; i < 4; ++i) {
    int nl = ty + 8 * i;
    float v = tile[tx][nl];
    unsigned short h = f32_to_bf16(v);
    unsigned short l = f32_to_bf16(v - bf16_to_f32(h));
    size_t q = (size_t)b * N_ + n0 + nl;
    xh[q * D_ + d0 + tx] = h;
    xl[q * D_ + d0 + tx] = l;
  }
}

// Split e [K, D] into bf16 hi/lo; compute 0.5*||e_k||^2 in fp32.
__global__ void prep_e_kernel(const float* __restrict__ e,
                              unsigned short* __restrict__ eh,
                              unsigned short* __restrict__ el,
                              float* __restrict__ e2h) {
  int k = blockIdx.x;
  int d = threadIdx.x;  // 256 threads
  float v = e[(size_t)k * D_ + d];
  unsigned short h = f32_to_bf16(v);
  unsigned short l = f32_to_bf16(v - bf16_to_f32(h));
  eh[(size_t)k * D_ + d] = h;
  el[(size_t)k * D_ + d] = l;
  float s = v * v;
#pragma unroll
  for (int off = 32; off > 0; off >>= 1) s += __shfl_down(s, off, 64);
  __shared__ float ws4[4];
  if ((threadIdx.x & 63) == 0) ws4[threadIdx.x >> 6] = s;
  __syncthreads();
  if (threadIdx.x == 0) e2h[k] = 0.5f * (ws4[0] + ws4[1] + ws4[2] + ws4[3]);
}

// Main: per block = 128 queries x 4096 codes (K-split 2).
// 8 waves: wave wv handles query rows [wv*16, wv*16+16).
// d2_hat = 0.5*e2[k] - x.e_k ; argmin via running per-lane min + shuffle
// butterfly + packed u64 atomicMin across K-split blocks.
__global__ __launch_bounds__(512, 2) void vq_main_kernel(
    const unsigned short* __restrict__ xh, const unsigned short* __restrict__ xl,
    const unsigned short* __restrict__ eh, const unsigned short* __restrict__ el,
    const float* __restrict__ e2h, unsigned long long* __restrict__ keys) {
  // [buf][half(hi/lo)][code][d], stride 40 (80B) keeps 16B align + 2-way-max bank alias
  __shared__ unsigned short Bs[2][2][64][40];
  __shared__ float E2s[2][64];

  int tid = threadIdx.x;
  int lane = tid & 63;
  int wv = tid >> 6;       // 0..7
  int m = lane & 15;
  int quad = lane >> 4;

  int qt = blockIdx.x >> 1;
  int ks = blockIdx.x & 1;
  int q0 = qt * 128;
  int kbase = ks * 4096;

  // staging roles: threads 0..255 stage hi, 256..511 stage lo
  int half = tid >> 8;
  int st = tid & 255;
  int srow = st >> 2;            // code row 0..63
  int scol = (st & 3) * 8;       // d offset (elements)
  const unsigned short* esrc = half ? el : eh;

  // Persistent A fragments: 16 queries x 256 d (hi+lo) per wave, in registers.
  int q = q0 + wv * 16 + m;
  bf16x8 ah[8], al[8];
#pragma unroll
  for (int s = 0; s < 8; ++s) {
    ah[s] = *(const bf16x8*)(xh + (size_t)q * D_ + s * 32 + quad * 8);
    al[s] = *(const bf16x8*)(xl + (size_t)q * D_ + s * 32 + quad * 8);
  }

  float rminv[4][4];
  int rmini[4][4];
#pragma unroll
  for (int t = 0; t < 4; ++t)
#pragma unroll
    for (int r = 0; r < 4; ++r) { rminv[t][r] = __builtin_inff(); rmini[t][r] = 0; }

  auto stage = [&](int it2) {
    int ch2 = it2 >> 3, s2 = it2 & 7, b2 = it2 & 1;
    int kc2 = kbase + ch2 * 64;
    bf16x8 v = *(const bf16x8*)(esrc + (size_t)(kc2 + srow) * D_ + s2 * 32 + scol);
    *(bf16x8*)&Bs[b2][half][srow][scol] = v;
    if (s2 == 0 && tid < 64) E2s[ch2 & 1][tid] = e2h[kc2 + tid];
  };

  stage(0);
  __syncthreads();

#pragma unroll 1
  for (int ch = 0; ch < 64; ++ch) {
    f32x4 acc[4];
#pragma unroll
    for (int t = 0; t < 4; ++t) acc[t] = (f32x4){0.f, 0.f, 0.f, 0.f};
#pragma unroll
    for (int s = 0; s < 8; ++s) {
      int it = ch * 8 + s;
      int buf = it & 1;
      if (it + 1 < 512) stage(it + 1);
      bf16x8 bh[4], bl[4];
#pragma unroll
      for (int t = 0; t < 4; ++t) {
        bh[t] = *(const bf16x8*)&Bs[buf][0][t * 16 + m][quad * 8];
        bl[t] = *(const bf16x8*)&Bs[buf][1][t * 16 + m][quad * 8];
      }
#pragma unroll
      for (int t = 0; t < 4; ++t) {
        acc[t] = __builtin_amdgcn_mfma_f32_16x16x32_bf16(ah[s], bh[t], acc[t], 0, 0, 0);
        acc[t] = __builtin_amdgcn_mfma_f32_16x16x32_bf16(ah[s], bl[t], acc[t], 0, 0, 0);
        acc[t] = __builtin_amdgcn_mfma_f32_16x16x32_bf16(al[s], bh[t], acc[t], 0, 0, 0);
      }
      __syncthreads();
    }
    // epilogue: d = 0.5*e2[k] - S ; running min per (tile, reg)
    int kc = kbase + ch * 64;
#pragma unroll
    for (int t = 0; t < 4; ++t) {
      float e2v = E2s[ch & 1][t * 16 + m];
      int kidx = kc + t * 16 + m;
#pragma unroll
      for (int r = 0; r < 4; ++r) {
        float dv = e2v - acc[t][r];
        bool better = dv < rminv[t][r];      // strict <: earlier (smaller) idx wins ties
        rminv[t][r] = better ? dv : rminv[t][r];
        rmini[t][r] = better ? kidx : rmini[t][r];
      }
    }
  }

  // Final reduction: in-lane over tiles, butterfly over the 16-lane column group,
  // then packed (sortable-float << 32 | idx) atomicMin across K-split blocks.
#pragma unroll
  for (int r = 0; r < 4; ++r) {
    float bv = rminv[0][r];
    int bi = rmini[0][r];
#pragma unroll
    for (int t = 1; t < 4; ++t) {
      if (rminv[t][r] < bv) { bv = rminv[t][r]; bi = rmini[t][r]; }
    }
#pragma unroll
    for (int xm = 1; xm <= 8; xm <<= 1) {
      float ov = __shfl_xor(bv, xm, 64);
      int oi = __shfl_xor(bi, xm, 64);
      if (ov < bv || (ov == bv && oi < bi)) { bv = ov; bi = oi; }
    }
    if (m == 0) {
      int qq = q0 + wv * 16 + quad * 4 + r;
      unsigned su = __float_as_uint(bv);
      su ^= (unsigned)(((int)su >> 31) | 0x80000000u);
      unsigned long long key = ((unsigned long long)su << 32) | (unsigned)bi;
      atomicMin(keys + qq, key);
    }
  }
}

// out[b][d][n] = e[code[b,n]][d]
__global__ void decode_kernel(const unsigned long long* __restrict__ keys,
                              const float* __restrict__ e,
                              float* __restrict__ out) {
  size_t gid = (size_t)blockIdx.x * 256 + threadIdx.x;
  int n = (int)(gid % N_);
  int rest = (int)(gid / N_);
  int d = rest % D_;
  int b = rest / D_;
  unsigned idx = (unsigned)(keys[(size_t)b * N_ + n] & 0xFFFFFFFFull);
  out[gid] = e[(size_t)idx * D_ + d];
}

extern "C" void kernel_launch(void* const* d_in, const int* in_sizes, int n_in,
                              void* d_out, int out_size, void* d_ws, size_t ws_size,
                              hipStream_t stream) {
  const float* x = (const float*)d_in[0];
  const float* e = (const float*)d_in[1];
  float* out = (float*)d_out;

  // workspace layout (~25.3 MB total)
  char* w = (char*)d_ws;
  unsigned short* xh = (unsigned short*)w;                      // 8 MB
  unsigned short* xl = xh + (size_t)Q_ * D_;                    // 8 MB
  unsigned short* eh = xl + (size_t)Q_ * D_;                    // 4 MB
  unsigned short* el = eh + (size_t)K_ * D_;                    // 4 MB
  float* e2h = (float*)(el + (size_t)K_ * D_);                  // 32 KB
  unsigned long long* keys = (unsigned long long*)(e2h + K_);   // 128 KB

  hipMemsetAsync(keys, 0xFF, (size_t)Q_ * sizeof(unsigned long long), stream);
  prep_x_kernel<<<dim3(N_ / 32, D_ / 32, B_), dim3(32, 8), 0, stream>>>(x, xh, xl);
  prep_e_kernel<<<K_, 256, 0, stream>>>(e, eh, el, e2h);
  vq_main_kernel<<<256, 512, 0, stream>>>(xh, xl, eh, el, e2h, keys);
  decode_kernel<<<(Q_ * D_) / 256, 256, 0, stream>>>(keys, e, out);
}

// Round 2
// 260.567 us; speedup vs baseline: 1.3812x; 1.3812x over previous
//
#include <hip/hip_runtime.h>
#include <stdint.h>

#define B_ 4
#define D_ 256
#define N_ 4096
#define K_ 8192
#define Q_ (B_*N_)   // 16384 queries

typedef __attribute__((ext_vector_type(8))) short bf16x8;
typedef __attribute__((ext_vector_type(16))) float f32x16;

__device__ __forceinline__ unsigned short f32_to_bf16(float f) {
  unsigned u = __float_as_uint(f);
  unsigned r = 0x7FFFu + ((u >> 16) & 1u);
  return (unsigned short)((u + r) >> 16);
}
__device__ __forceinline__ float bf16_to_f32(unsigned short h) {
  return __uint_as_float(((unsigned)h) << 16);
}

// async global->LDS, 16B per lane; LDS dest is wave-uniform base + lane*16
__device__ __forceinline__ void gl_lds16(const void* g, void* l) {
  __builtin_amdgcn_global_load_lds(
      (const __attribute__((address_space(1))) unsigned int*)g,
      (__attribute__((address_space(3))) unsigned int*)l, 16, 0, 0);
}

// Transpose x [B, D, N] -> xh/xl [Q=B*N, D] bf16 hi/lo split.
__global__ void prep_x_kernel(const float* __restrict__ x,
                              unsigned short* __restrict__ xh,
                              unsigned short* __restrict__ xl) {
  __shared__ float tile[32][33];
  int b = blockIdx.z;
  int d0 = blockIdx.y * 32;
  int n0 = blockIdx.x * 32;
  int tx = threadIdx.x, ty = threadIdx.y;
  const float* xp = x + ((size_t)b * D_ + d0) * N_ + n0;
#pragma unroll
  for (int i = 0; i < 4; ++i)
    tile[ty + 8 * i][tx] = xp[(size_t)(ty + 8 * i) * N_ + tx];
  __syncthreads();
#pragma unroll
  for (int i = 0; i < 4; ++i) {
    int nl = ty + 8 * i;
    float v = tile[tx][nl];
    unsigned short h = f32_to_bf16(v);
    unsigned short l = f32_to_bf16(v - bf16_to_f32(h));
    size_t q = (size_t)b * N_ + n0 + nl;
    xh[q * D_ + d0 + tx] = h;
    xl[q * D_ + d0 + tx] = l;
  }
}

// Split e [K, D] into bf16 hi/lo; compute 0.5*||e_k||^2; init keys.
__global__ void prep_e_kernel(const float* __restrict__ e,
                              unsigned short* __restrict__ eh,
                              unsigned short* __restrict__ el,
                              float* __restrict__ e2h,
                              unsigned long long* __restrict__ keys) {
  int k = blockIdx.x;
  int d = threadIdx.x;  // 256 threads
  if (d < 2) keys[(size_t)k * 2 + d] = ~0ull;  // Q_ = 2*K_
  float v = e[(size_t)k * D_ + d];
  unsigned short h = f32_to_bf16(v);
  unsigned short l = f32_to_bf16(v - bf16_to_f32(h));
  eh[(size_t)k * D_ + d] = h;
  el[(size_t)k * D_ + d] = l;
  float s = v * v;
#pragma unroll
  for (int off = 32; off > 0; off >>= 1) s += __shfl_down(s, off, 64);
  __shared__ float ws4[4];
  if ((threadIdx.x & 63) == 0) ws4[threadIdx.x >> 6] = s;
  __syncthreads();
  if (threadIdx.x == 0) e2h[k] = 0.5f * (ws4[0] + ws4[1] + ws4[2] + ws4[3]);
}

// Main: block = 256 queries x 2048 codes (K-split 4), 8 waves x 32 queries.
// Per chunk: 32 codes x 256 d (hi+lo) staged via global_load_lds (async DMA),
// XOR-swizzled layout; 48 MFMAs (32x32x16) per wave per chunk; one barrier
// per chunk. d2_hat = 0.5*e2[k] - x.e_k; running min; u64 atomicMin merge.
__global__ __launch_bounds__(512, 2) void vq_main_kernel(
    const unsigned short* __restrict__ xh, const unsigned short* __restrict__ xl,
    const unsigned short* __restrict__ eh, const unsigned short* __restrict__ el,
    const float* __restrict__ e2h, unsigned long long* __restrict__ keys) {
  // [buf][half][code*256 + swizzled runs]; 64 KB total, dense (DMA-compatible).
  // run g of code c lives at 16B-slot (g ^ (c&31)) within the code's 512 B row.
  __shared__ __attribute__((aligned(16))) unsigned short Bs[2][2][32 * 256];

  const int tid = threadIdx.x;
  const int w = tid >> 6;       // wave 0..7
  const int lane = tid & 63;
  const int l = lane & 31;      // spatial index (code col / query row)
  const int hi = lane >> 5;     // k-group half

  const int qt = blockIdx.x >> 2;
  const int ks4 = blockIdx.x & 3;
  const int q0 = qt * 256;
  const int kbase = ks4 * 2048;
  const int qw = q0 + w * 32;

  // Persistent A fragments: 32 queries x 256 d, hi+lo. A[m=lane&31][k=hi*8+j].
  bf16x8 ah[16], al[16];
  {
    const unsigned short* pa = xh + (size_t)(qw + l) * D_ + hi * 8;
    const unsigned short* pb = xl + (size_t)(qw + l) * D_ + hi * 8;
#pragma unroll
    for (int kc16 = 0; kc16 < 16; ++kc16) {
      ah[kc16] = *(const bf16x8*)(pa + kc16 * 16);
      al[kc16] = *(const bf16x8*)(pb + kc16 * 16);
    }
  }

  float rminv[16];
  int rmini[16];
#pragma unroll
  for (int r = 0; r < 16; ++r) { rminv[r] = __builtin_inff(); rmini[r] = 0; }

  // Stage chunk ch into buf: wave w loads codes [w*4, w*4+4), both halves.
  // One instr = 64 lanes x 16B = 2 code rows. Swizzle via source address.
  auto stage = [&](int ch, int buf) {
    const int kc = kbase + ch * 32;
#pragma unroll
    for (int p = 0; p < 2; ++p) {
      const int c0 = w * 4 + p * 2;
      const int c = c0 + hi;
      const int g = l ^ (c & 31);
      const size_t srcoff = (size_t)(kc + c) * D_ + g * 8;
      gl_lds16(eh + srcoff, &Bs[buf][0][c0 * 256]);
      gl_lds16(el + srcoff, &Bs[buf][1][c0 * 256]);
    }
  };

  stage(0, 0);

#pragma unroll 1
  for (int ch = 0; ch < 64; ++ch) {
    const int buf = ch & 1;
    __syncthreads();                    // drains DMA for chunk ch (vmcnt 0)
    if (ch + 1 < 64) stage(ch + 1, buf ^ 1);
    const int kc = kbase + ch * 32;
    const float e2v = e2h[kc + l];      // issue early; L1/L2-hot

    f32x16 acc;
#pragma unroll
    for (int r = 0; r < 16; ++r) acc[r] = 0.f;

#pragma unroll
    for (int ks = 0; ks < 16; ++ks) {
      const int pos = (((ks * 2 + hi) ^ l) * 8);
      bf16x8 bh = *(const bf16x8*)&Bs[buf][0][l * 256 + pos];
      bf16x8 bl = *(const bf16x8*)&Bs[buf][1][l * 256 + pos];
      acc = __builtin_amdgcn_mfma_f32_32x32x16_bf16(ah[ks], bh, acc, 0, 0, 0);
      acc = __builtin_amdgcn_mfma_f32_32x32x16_bf16(ah[ks], bl, acc, 0, 0, 0);
      acc = __builtin_amdgcn_mfma_f32_32x32x16_bf16(al[ks], bh, acc, 0, 0, 0);
    }

    const int kidx = kc + l;  // all 16 acc regs share the same code column
#pragma unroll
    for (int r = 0; r < 16; ++r) {
      float dv = e2v - acc[r];
      bool better = dv < rminv[r];
      rminv[r] = better ? dv : rminv[r];
      rmini[r] = better ? kidx : rmini[r];
    }
  }

  // Reduce over the 32 code-columns within each half-wave, then cross-block
  // merge via packed (sortable-float<<32 | idx) u64 atomicMin.
#pragma unroll
  for (int r = 0; r < 16; ++r) {
    float bv = rminv[r];
    int bi = rmini[r];
#pragma unroll
    for (int xm = 1; xm <= 16; xm <<= 1) {
      float ov = __shfl_xor(bv, xm, 64);
      int oi = __shfl_xor(bi, xm, 64);
      if (ov < bv || (ov == bv && oi < bi)) { bv = ov; bi = oi; }
    }
    if (l == 0) {
      const int m = (r & 3) + 8 * (r >> 2) + 4 * hi;  // C/D row mapping (m74/m101)
      const int qq = qw + m;
      unsigned su = __float_as_uint(bv);
      su ^= (unsigned)(((int)su >> 31) | 0x80000000u);
      unsigned long long key = ((unsigned long long)su << 32) | (unsigned)bi;
      atomicMin(keys + qq, key);
    }
  }
}

// out[b][d][n] = e[code[b,n]][d]
__global__ void decode_kernel(const unsigned long long* __restrict__ keys,
                              const float* __restrict__ e,
                              float* __restrict__ out) {
  size_t gid = (size_t)blockIdx.x * 256 + threadIdx.x;
  int n = (int)(gid % N_);
  int rest = (int)(gid / N_);
  int d = rest % D_;
  int b = rest / D_;
  unsigned idx = (unsigned)(keys[(size_t)b * N_ + n] & 0xFFFFFFFFull);
  out[gid] = e[(size_t)idx * D_ + d];
}

extern "C" void kernel_launch(void* const* d_in, const int* in_sizes, int n_in,
                              void* d_out, int out_size, void* d_ws, size_t ws_size,
                              hipStream_t stream) {
  const float* x = (const float*)d_in[0];
  const float* e = (const float*)d_in[1];
  float* out = (float*)d_out;

  // workspace layout (~24.2 MB)
  char* wksp = (char*)d_ws;
  unsigned short* xh = (unsigned short*)wksp;                   // 8 MB
  unsigned short* xl = xh + (size_t)Q_ * D_;                    // 8 MB
  unsigned short* eh = xl + (size_t)Q_ * D_;                    // 4 MB
  unsigned short* el = eh + (size_t)K_ * D_;                    // 4 MB
  float* e2h = (float*)(el + (size_t)K_ * D_);                  // 32 KB
  unsigned long long* keys = (unsigned long long*)(e2h + K_);   // 128 KB

  prep_x_kernel<<<dim3(N_ / 32, D_ / 32, B_), dim3(32, 8), 0, stream>>>(x, xh, xl);
  prep_e_kernel<<<K_, 256, 0, stream>>>(e, eh, el, e2h, keys);
  vq_main_kernel<<<256, 512, 0, stream>>>(xh, xl, eh, el, e2h, keys);
  decode_kernel<<<(Q_ * D_) / 256, 256, 0, stream>>>(keys, e, out);
}